// Round 3
// baseline (159.650 us; speedup 1.0000x reference)
//
#include <hip/hip_runtime.h>
#include <hip/hip_bf16.h>

// CARNN: 9-step RNN (D=64) + projection to 300 actions, BATCH=65536.
// R8: kill re-introduced L2 hot-line contention. Barrier-free RNN kept
// (wave-private H, lgkmcnt-only). Step-8 weights prefetched into REGISTERS
// during step 7 (M8 at entry, W8 after MFMAs -> VGPR peak staged). After
// the RNN the 120KB weight LDS is dead: barrier, restage out_w (40KB) +
// outb there via global_load_lds, barrier, projection reads linear LDS.
// Nontemporal f32x4 output stores. 3 barriers total.

#define SEQ     9
#define DMODEL  64
#define ANUM    300

// ws layout (bf16 element offsets) -- unchanged, prepack identical
#define WS_MW   0        // 9*8192: per step [kind(M=0,W=1)][nt][kb][lane][8]
#define WS_OW   73728    // 5*4096: [cc][nt][kb][lane][8]
#define WS_EMB  94208    // 301*64 bf16 emb table
#define WS_END  113472
#define WS_BSUM_BYTES (WS_END * 2)

// LDS layout (shorts): weights s0M(4096) + s1..7(7*8192) | bsum | scratch
#define BSOFF   61440
#define HSOFF   62592     // 16 waves x 1024 shorts (2KB each)
#define SLTOT   78976     // 157,952 bytes

typedef __attribute__((ext_vector_type(8))) short  bf16x8;
typedef __attribute__((ext_vector_type(4))) float  f32x4;

#define MFMA __builtin_amdgcn_mfma_f32_16x16x32_bf16

__device__ __forceinline__ unsigned short f2b(float f) {
    union { float f; unsigned int u; } x; x.f = f;
    unsigned int r = x.u + 0x7FFFu + ((x.u >> 16) & 1u);
    return (unsigned short)(r >> 16);
}

__device__ __forceinline__ float sigmoid_fast(float v) {
    return __builtin_amdgcn_rcpf(1.f + __expf(-v));
}

// async global->LDS, 16 B per lane; lds base must be wave-uniform
__device__ __forceinline__ void async16(const unsigned short* g, unsigned short* l) {
    __builtin_amdgcn_global_load_lds(
        (const __attribute__((address_space(1))) unsigned int*)g,
        (__attribute__((address_space(3))) unsigned int*)l, 16, 0, 0);
}

// ---------------- pre-pass: convert + pack (unchanged) ----------------
#define PP_TOTAL (73728 + 20480 + 19264 + 576)

__global__ void prepack(const float* __restrict__ Mw, const float* __restrict__ Ww,
                        const float* __restrict__ outw, const float* __restrict__ emb,
                        const float* __restrict__ Mb, const float* __restrict__ Wb,
                        unsigned short* __restrict__ wsb, float* __restrict__ bsum)
{
    int t = blockIdx.x * 256 + threadIdx.x;
    if (t < 73728) {                       // M+W, step-major 16KB blocks
        int s    = t >> 13;
        int r    = t & 8191;
        int kind = r >> 12;
        int f    = r & 4095;
        int nt   = f >> 10;
        int kb   = (f >> 9) & 1;
        int lane = (f >> 3) & 63;
        int j    = f & 7;
        int nr   = nt * 16 + (lane & 15);
        int k    = kb * 32 + ((lane >> 4) << 3) + j;
        const float* src = kind ? Ww : Mw;
        wsb[WS_MW + t] = f2b(src[(s * DMODEL + nr) * DMODEL + k]);
        return;
    }
    t -= 73728;
    if (t < 20480) {                       // outw fragments
        int j    = t & 7;
        int lane = (t >> 3) & 63;
        int kb   = (t >> 9) & 1;
        int nt   = (t >> 10) & 3;
        int cc   = t >> 12;
        int col  = cc * 64 + nt * 16 + (lane & 15);
        int k    = kb * 32 + ((lane >> 4) << 3) + j;
        float v  = (col < ANUM) ? outw[col * DMODEL + k] : 0.f;
        wsb[WS_OW + t] = f2b(v);
        return;
    }
    t -= 20480;
    if (t < 19264) { wsb[WS_EMB + t] = f2b(emb[t]); return; }
    t -= 19264;
    if (t < 576)   { bsum[t] = Mb[t] + Wb[t]; }
}

// ---------------- main ----------------
__global__ __launch_bounds__(1024, 4)
void carnn_main(const int* __restrict__ acts,
                const unsigned short* __restrict__ wsb,
                const float* __restrict__ bsum,
                const float* __restrict__ outb,
                float* __restrict__ out)
{
    __shared__ __align__(16) unsigned short SL[SLTOT];

    const int tid  = threadIdx.x;
    const int lane = tid & 63;
    const int wv   = tid >> 6;         // 0..15
    const int lrow = lane & 15;        // batch row within wave (B-operand n)
    const int quad = lane >> 4;

    const int brow = (blockIdx.x * 16 + wv) * 16 + lrow;   // global batch row
    const int rowS = brow * SEQ;

    // ---- stage weights s0M + s1..7 (120 chunks of 1KB) ----
    for (int c = wv; c < 120; c += 16) {
        const int goff = (c < 8) ? (c * 512) : ((c + 8) * 512);
        async16(wsb + WS_MW + goff + lane * 8, &SL[c * 512]);
    }
    // ---- stage bsum (2304 B) ----
    {
        const unsigned short* bs = (const unsigned short*)bsum;
        if (wv == 13) async16(bs + lane * 8,         &SL[BSOFF]);
        if (wv == 14) async16(bs + 512 + lane * 8,   &SL[BSOFF + 512]);
        if (wv == 15 && lane < 16)
                      async16(bs + 1024 + lane * 8,  &SL[BSOFF + 1024]);
    }

    // step-0 inputs (overlap with staging)
    const unsigned short* Eb = wsb + WS_EMB;
    int idc = acts[rowS];
    bf16x8 xc0 = *(const bf16x8*)(Eb + idc * DMODEL + quad * 8);
    bf16x8 xc1 = *(const bf16x8*)(Eb + idc * DMODEL + 32 + quad * 8);
    int idn = acts[rowS + 1];

    // per-wave H scratch: 2KB, XOR-swizzled (conflict-free b64 w / b128 r)
    char* const SB = (char*)SL;
    const int swz    = (lrow & 7) << 4;
    const int hbyte  = HSOFF * 2 + wv * 2048 + lrow * 128;
    const int rbyte0 = hbyte + ((quad * 16) ^ swz);          // kb0
    const int rbyte1 = hbyte + ((64 + quad * 16) ^ swz);     // kb1

    __syncthreads();    // barrier #1: weights + bsum staged

    const float* BSf = (const float*)&SL[BSOFF];
    bf16x8 s8m[8], s8w[8];   // step-8 weight frags, register-prefetched

    #pragma unroll
    for (int s = 0; s < SEQ; ++s) {
        // prefetch next step's x fragments (id already resident)
        bf16x8 xn0, xn1;
        if (s + 1 < SEQ) {
            xn0 = *(const bf16x8*)(Eb + idn * DMODEL + quad * 8);
            xn1 = *(const bf16x8*)(Eb + idn * DMODEL + 32 + quad * 8);
            if (s + 2 < SEQ) idn = acts[rowS + s + 2];
        }
        // issue M8 register prefetch at step-7 entry (covered by step 7)
        if (s == 7) {
            const unsigned short* G8 = wsb + WS_MW + 8 * 8192;
            #pragma unroll
            for (int q2 = 0; q2 < 4; ++q2) {
                s8m[q2 * 2]     = *(const bf16x8*)(G8 + q2 * 1024 + lane * 8);
                s8m[q2 * 2 + 1] = *(const bf16x8*)(G8 + q2 * 1024 + 512 + lane * 8);
            }
        }
        // previous-step H fragments (B-operand), wave-private
        bf16x8 h0, h1;
        if (s > 0) {
            h0 = *(const bf16x8*)(SB + rbyte0);
            h1 = *(const bf16x8*)(SB + rbyte1);
        }
        // weight fragment base in LDS (s<8); s8 comes from registers
        const unsigned short* WB = (s == 0) ? &SL[0] : &SL[4096 + (s - 1) * 8192];

        #pragma unroll
        for (int nt = 0; nt < 4; ++nt) {
            bf16x8 am0, am1;
            if (s < 8) {
                const unsigned short* Mf = WB + nt * 1024 + lane * 8;
                am0 = *(const bf16x8*)Mf;
                am1 = *(const bf16x8*)(Mf + 512);
            } else {
                am0 = s8m[nt * 2];
                am1 = s8m[nt * 2 + 1];
            }
            // acc init = bias vector (feats nt*16+quad*4 .. +3)
            f32x4 acc = *(const f32x4*)(BSf + s * 64 + nt * 16 + quad * 4);
            acc = MFMA(am0, xc0, acc, 0, 0, 0);   // A=weights, B=x (swapped)
            acc = MFMA(am1, xc1, acc, 0, 0, 0);
            if (s > 0) {
                bf16x8 aw0, aw1;
                if (s < 8) {
                    const unsigned short* Wf = WB + 4096 + nt * 1024 + lane * 8;
                    aw0 = *(const bf16x8*)Wf;
                    aw1 = *(const bf16x8*)(Wf + 512);
                } else {
                    aw0 = s8w[nt * 2];
                    aw1 = s8w[nt * 2 + 1];
                }
                acc = MFMA(aw0, h0, acc, 0, 0, 0);
                acc = MFMA(aw1, h1, acc, 0, 0, 0);
            }
            // sigmoid -> bf16 pack -> one b64 write (4 consecutive feats)
            unsigned int u0 = (unsigned int)f2b(sigmoid_fast(acc[0]))
                            | ((unsigned int)f2b(sigmoid_fast(acc[1])) << 16);
            unsigned int u1 = (unsigned int)f2b(sigmoid_fast(acc[2]))
                            | ((unsigned int)f2b(sigmoid_fast(acc[3])) << 16);
            *(uint2*)(SB + hbyte + ((nt * 32 + quad * 8) ^ swz)) = make_uint2(u0, u1);
        }
        // issue W8 register prefetch after step-7 compute (lower VGPR peak)
        if (s == 7) {
            const unsigned short* G8 = wsb + WS_MW + 8 * 8192 + 4096;
            #pragma unroll
            for (int q2 = 0; q2 < 4; ++q2) {
                s8w[q2 * 2]     = *(const bf16x8*)(G8 + q2 * 1024 + lane * 8);
                s8w[q2 * 2 + 1] = *(const bf16x8*)(G8 + q2 * 1024 + 512 + lane * 8);
            }
        }
        if (s + 1 < SEQ) { xc0 = xn0; xc1 = xn1; }
        // NO barrier -- H is wave-private, lgkmcnt orders write->read
    }

    // final H fragments (same-wave lgkm ordering)
    bf16x8 h0 = *(const bf16x8*)(SB + rbyte0);
    bf16x8 h1 = *(const bf16x8*)(SB + rbyte1);

    // ---- restage: out_w (40KB) into dead weight region, outb into bsum ----
    __syncthreads();    // barrier #2: weight + bsum regions now dead
    for (int c = wv; c < 40; c += 16)
        async16(wsb + WS_OW + c * 512 + lane * 8, &SL[c * 512]);
    {
        const unsigned short* ob = (const unsigned short*)outb;
        if (wv == 12)               async16(ob + lane * 8,       &SL[BSOFF]);
        if (wv == 13 && lane < 11)  async16(ob + 512 + lane * 8, &SL[BSOFF + 512]);
    }
    __syncthreads();    // barrier #3: projection data staged

    const float* OBf = (const float*)&SL[BSOFF];
    float* orow = out + brow * ANUM;   // lane's batch row

    #pragma unroll
    for (int t = 0; t < 19; ++t) {     // 19 x 16-col tiles cover 304 cols
        const int cc = t >> 2, nt = t & 3;
        const unsigned short* Of = &SL[cc * 4096 + nt * 1024 + lane * 8];
        bf16x8 a0 = *(const bf16x8*)Of;
        bf16x8 a1 = *(const bf16x8*)(Of + 512);
        const int col0 = cc * 64 + nt * 16 + quad * 4;

        f32x4 acc;
        if (col0 < ANUM) acc = *(const f32x4*)(OBf + col0);
        else             acc = (f32x4){0.f, 0.f, 0.f, 0.f};
        acc = MFMA(a0, h0, acc, 0, 0, 0);
        acc = MFMA(a1, h1, acc, 0, 0, 0);

        if (col0 < ANUM)               // col0 mult of 4, ANUM=300 mult of 4
            __builtin_nontemporal_store(acc, (f32x4*)(orow + col0));
    }
}

extern "C" void kernel_launch(void* const* d_in, const int* in_sizes, int n_in,
                              void* d_out, int out_size, void* d_ws, size_t ws_size,
                              hipStream_t stream) {
    const int*   acts = (const int*)  d_in[0];
    const float* emb  = (const float*)d_in[1];
    const float* Mw   = (const float*)d_in[2];
    const float* Mb   = (const float*)d_in[3];
    const float* Ww   = (const float*)d_in[4];
    const float* Wb   = (const float*)d_in[5];
    const float* outw = (const float*)d_in[6];
    const float* outb = (const float*)d_in[7];
    float* out = (float*)d_out;
    (void)in_sizes; (void)n_in; (void)ws_size; (void)out_size;

    unsigned short* wsb = (unsigned short*)d_ws;
    float* bsum = (float*)((char*)d_ws + WS_BSUM_BYTES);

    prepack<<<(PP_TOTAL + 255) / 256, 256, 0, stream>>>(Mw, Ww, outw, emb, Mb, Wb, wsb, bsum);
    carnn_main<<<65536 / 256, 1024, 0, stream>>>(acts, wsb, bsum, outb, out);
}

// Round 5
// 119.362 us; speedup vs baseline: 1.3375x; 1.3375x over previous
//
#include <hip/hip_runtime.h>
#include <hip/hip_bf16.h>

// CARNN: 9-step RNN (D=64) + projection to 300 actions, BATCH=65536.
// R9 (resubmit; previous round failed on container acquisition, kernel
// never ran). Selective revert of R8. KEEP: projection out_w+outb
// restaged into the dead weight-LDS region (R8's FETCH counter proved
// -95% L2 reads). REVERT: nontemporal stores (1.6x write amplification,
// 1.77 TB/s drain -> plain f32x4 stores that coalesce in L2) and s8
// register prefetch (VGPR churn; step-8 frags read from L2 as in R7,
// which measured fine). Barrier-free RNN unchanged: wave-private
// XOR-swizzled H, lgkmcnt-only ordering, 3 barriers total.

#define SEQ     9
#define DMODEL  64
#define ANUM    300

// ws layout (bf16 element offsets) -- unchanged, prepack identical
#define WS_MW   0        // 9*8192: per step [kind(M=0,W=1)][nt][kb][lane][8]
#define WS_OW   73728    // 5*4096: [cc][nt][kb][lane][8]
#define WS_EMB  94208    // 301*64 bf16 emb table
#define WS_END  113472
#define WS_BSUM_BYTES (WS_END * 2)

// LDS layout (shorts): weights s0M(4096) + s1..7(7*8192) | bsum | scratch
#define BSOFF   61440
#define HSOFF   62592     // 16 waves x 1024 shorts (2KB each)
#define SLTOT   78976     // 157,952 bytes

typedef __attribute__((ext_vector_type(8))) short  bf16x8;
typedef __attribute__((ext_vector_type(4))) float  f32x4;

#define MFMA __builtin_amdgcn_mfma_f32_16x16x32_bf16

__device__ __forceinline__ unsigned short f2b(float f) {
    union { float f; unsigned int u; } x; x.f = f;
    unsigned int r = x.u + 0x7FFFu + ((x.u >> 16) & 1u);
    return (unsigned short)(r >> 16);
}

__device__ __forceinline__ float sigmoid_fast(float v) {
    return __builtin_amdgcn_rcpf(1.f + __expf(-v));
}

// async global->LDS, 16 B per lane; lds base must be wave-uniform
__device__ __forceinline__ void async16(const unsigned short* g, unsigned short* l) {
    __builtin_amdgcn_global_load_lds(
        (const __attribute__((address_space(1))) unsigned int*)g,
        (__attribute__((address_space(3))) unsigned int*)l, 16, 0, 0);
}

// ---------------- pre-pass: convert + pack (unchanged) ----------------
#define PP_TOTAL (73728 + 20480 + 19264 + 576)

__global__ void prepack(const float* __restrict__ Mw, const float* __restrict__ Ww,
                        const float* __restrict__ outw, const float* __restrict__ emb,
                        const float* __restrict__ Mb, const float* __restrict__ Wb,
                        unsigned short* __restrict__ wsb, float* __restrict__ bsum)
{
    int t = blockIdx.x * 256 + threadIdx.x;
    if (t < 73728) {                       // M+W, step-major 16KB blocks
        int s    = t >> 13;
        int r    = t & 8191;
        int kind = r >> 12;
        int f    = r & 4095;
        int nt   = f >> 10;
        int kb   = (f >> 9) & 1;
        int lane = (f >> 3) & 63;
        int j    = f & 7;
        int nr   = nt * 16 + (lane & 15);
        int k    = kb * 32 + ((lane >> 4) << 3) + j;
        const float* src = kind ? Ww : Mw;
        wsb[WS_MW + t] = f2b(src[(s * DMODEL + nr) * DMODEL + k]);
        return;
    }
    t -= 73728;
    if (t < 20480) {                       // outw fragments
        int j    = t & 7;
        int lane = (t >> 3) & 63;
        int kb   = (t >> 9) & 1;
        int nt   = (t >> 10) & 3;
        int cc   = t >> 12;
        int col  = cc * 64 + nt * 16 + (lane & 15);
        int k    = kb * 32 + ((lane >> 4) << 3) + j;
        float v  = (col < ANUM) ? outw[col * DMODEL + k] : 0.f;
        wsb[WS_OW + t] = f2b(v);
        return;
    }
    t -= 20480;
    if (t < 19264) { wsb[WS_EMB + t] = f2b(emb[t]); return; }
    t -= 19264;
    if (t < 576)   { bsum[t] = Mb[t] + Wb[t]; }
}

// ---------------- main ----------------
__global__ __launch_bounds__(1024, 4)
void carnn_main(const int* __restrict__ acts,
                const unsigned short* __restrict__ wsb,
                const float* __restrict__ bsum,
                const float* __restrict__ outb,
                float* __restrict__ out)
{
    __shared__ __align__(16) unsigned short SL[SLTOT];

    const int tid  = threadIdx.x;
    const int lane = tid & 63;
    const int wv   = tid >> 6;         // 0..15
    const int lrow = lane & 15;        // batch row within wave (B-operand n)
    const int quad = lane >> 4;

    const int brow = (blockIdx.x * 16 + wv) * 16 + lrow;   // global batch row
    const int rowS = brow * SEQ;

    // ---- stage weights s0M + s1..7 (120 chunks of 1KB) ----
    for (int c = wv; c < 120; c += 16) {
        const int goff = (c < 8) ? (c * 512) : ((c + 8) * 512);
        async16(wsb + WS_MW + goff + lane * 8, &SL[c * 512]);
    }
    // ---- stage bsum (2304 B) ----
    {
        const unsigned short* bs = (const unsigned short*)bsum;
        if (wv == 13) async16(bs + lane * 8,         &SL[BSOFF]);
        if (wv == 14) async16(bs + 512 + lane * 8,   &SL[BSOFF + 512]);
        if (wv == 15 && lane < 16)
                      async16(bs + 1024 + lane * 8,  &SL[BSOFF + 1024]);
    }

    // step-0 inputs (overlap with staging)
    const unsigned short* Eb = wsb + WS_EMB;
    int idc = acts[rowS];
    bf16x8 xc0 = *(const bf16x8*)(Eb + idc * DMODEL + quad * 8);
    bf16x8 xc1 = *(const bf16x8*)(Eb + idc * DMODEL + 32 + quad * 8);
    int idn = acts[rowS + 1];

    // per-wave H scratch: 2KB, XOR-swizzled (conflict-free b64 w / b128 r)
    char* const SB = (char*)SL;
    const int swz    = (lrow & 7) << 4;
    const int hbyte  = HSOFF * 2 + wv * 2048 + lrow * 128;
    const int rbyte0 = hbyte + ((quad * 16) ^ swz);          // kb0
    const int rbyte1 = hbyte + ((64 + quad * 16) ^ swz);     // kb1

    __syncthreads();    // barrier #1: weights + bsum staged

    const float* BSf = (const float*)&SL[BSOFF];

    #pragma unroll
    for (int s = 0; s < SEQ; ++s) {
        // prefetch next step's x fragments (id already resident)
        bf16x8 xn0, xn1;
        if (s + 1 < SEQ) {
            xn0 = *(const bf16x8*)(Eb + idn * DMODEL + quad * 8);
            xn1 = *(const bf16x8*)(Eb + idn * DMODEL + 32 + quad * 8);
            if (s + 2 < SEQ) idn = acts[rowS + s + 2];
        }
        // previous-step H fragments (B-operand), wave-private
        bf16x8 h0, h1;
        if (s > 0) {
            h0 = *(const bf16x8*)(SB + rbyte0);
            h1 = *(const bf16x8*)(SB + rbyte1);
        }
        // weight fragment base: LDS for s<8, global (L2) for s8
        const unsigned short* WB;
        if (s == 0)     WB = &SL[0];
        else if (s < 8) WB = &SL[4096 + (s - 1) * 8192];
        else            WB = wsb + WS_MW + 8 * 8192;

        #pragma unroll
        for (int nt = 0; nt < 4; ++nt) {
            const unsigned short* Mf = WB + nt * 1024 + lane * 8;
            bf16x8 am0 = *(const bf16x8*)Mf;
            bf16x8 am1 = *(const bf16x8*)(Mf + 512);
            // acc init = bias vector (feats nt*16+quad*4 .. +3)
            f32x4 acc = *(const f32x4*)(BSf + s * 64 + nt * 16 + quad * 4);
            acc = MFMA(am0, xc0, acc, 0, 0, 0);   // A=weights, B=x (swapped)
            acc = MFMA(am1, xc1, acc, 0, 0, 0);
            if (s > 0) {
                const unsigned short* Wf = WB + 4096 + nt * 1024 + lane * 8;
                bf16x8 aw0 = *(const bf16x8*)Wf;
                bf16x8 aw1 = *(const bf16x8*)(Wf + 512);
                acc = MFMA(aw0, h0, acc, 0, 0, 0);
                acc = MFMA(aw1, h1, acc, 0, 0, 0);
            }
            // sigmoid -> bf16 pack -> one b64 write (4 consecutive feats)
            unsigned int u0 = (unsigned int)f2b(sigmoid_fast(acc[0]))
                            | ((unsigned int)f2b(sigmoid_fast(acc[1])) << 16);
            unsigned int u1 = (unsigned int)f2b(sigmoid_fast(acc[2]))
                            | ((unsigned int)f2b(sigmoid_fast(acc[3])) << 16);
            *(uint2*)(SB + hbyte + ((nt * 32 + quad * 8) ^ swz)) = make_uint2(u0, u1);
        }
        if (s + 1 < SEQ) { xc0 = xn0; xc1 = xn1; }
        // NO barrier -- H is wave-private, lgkmcnt orders write->read
    }

    // final H fragments (same-wave lgkm ordering)
    bf16x8 h0 = *(const bf16x8*)(SB + rbyte0);
    bf16x8 h1 = *(const bf16x8*)(SB + rbyte1);

    // ---- restage: out_w (40KB) into dead weight region, outb into bsum ----
    __syncthreads();    // barrier #2: weight + bsum regions now dead
    for (int c = wv; c < 40; c += 16)
        async16(wsb + WS_OW + c * 512 + lane * 8, &SL[c * 512]);
    {
        const unsigned short* ob = (const unsigned short*)outb;
        if (wv == 12)               async16(ob + lane * 8,       &SL[BSOFF]);
        if (wv == 13 && lane < 11)  async16(ob + 512 + lane * 8, &SL[BSOFF + 512]);
    }
    __syncthreads();    // barrier #3: projection data staged

    const float* OBf = (const float*)&SL[BSOFF];
    float* orow = out + brow * ANUM;   // lane's batch row

    #pragma unroll
    for (int t = 0; t < 19; ++t) {     // 19 x 16-col tiles cover 304 cols
        const int cc = t >> 2, nt = t & 3;
        const unsigned short* Of = &SL[cc * 4096 + nt * 1024 + lane * 8];
        bf16x8 a0 = *(const bf16x8*)Of;
        bf16x8 a1 = *(const bf16x8*)(Of + 512);
        const int col0 = cc * 64 + nt * 16 + quad * 4;

        f32x4 acc;
        if (col0 < ANUM) acc = *(const f32x4*)(OBf + col0);
        else             acc = (f32x4){0.f, 0.f, 0.f, 0.f};
        acc = MFMA(a0, h0, acc, 0, 0, 0);
        acc = MFMA(a1, h1, acc, 0, 0, 0);

        if (col0 < ANUM)               // col0 mult of 4, ANUM=300 mult of 4
            *(f32x4*)(orow + col0) = acc;   // plain store: L2-coalesced
    }
}

extern "C" void kernel_launch(void* const* d_in, const int* in_sizes, int n_in,
                              void* d_out, int out_size, void* d_ws, size_t ws_size,
                              hipStream_t stream) {
    const int*   acts = (const int*)  d_in[0];
    const float* emb  = (const float*)d_in[1];
    const float* Mw   = (const float*)d_in[2];
    const float* Mb   = (const float*)d_in[3];
    const float* Ww   = (const float*)d_in[4];
    const float* Wb   = (const float*)d_in[5];
    const float* outw = (const float*)d_in[6];
    const float* outb = (const float*)d_in[7];
    float* out = (float*)d_out;
    (void)in_sizes; (void)n_in; (void)ws_size; (void)out_size;

    unsigned short* wsb = (unsigned short*)d_ws;
    float* bsum = (float*)((char*)d_ws + WS_BSUM_BYTES);

    prepack<<<(PP_TOTAL + 255) / 256, 256, 0, stream>>>(Mw, Ww, outw, emb, Mb, Wb, wsb, bsum);
    carnn_main<<<65536 / 256, 1024, 0, stream>>>(acts, wsb, bsum, outb, out);
}